// Round 1
// baseline (82.687 us; speedup 1.0000x reference)
//
#include <hip/hip_runtime.h>
#include <math.h>

// Reranker tie-aware RankNet loss.
// B=4096 rows, n=64 passages. One 64-lane wave per row:
//   - group-start index via wave cummax scan (== lax.cummax in the ref)
//   - mask (y_true[a] > y_true[b]) == (start[a] < start[b])  [int compare]
//   - per pair: softplus(pred[b] - pred[a]), accumulated in f32
// Two-stage deterministic reduction: per-block partials -> finalize kernel.

#define N 64
#define WAVES_PER_BLOCK 4
#define NBLOCKS 256

__device__ __forceinline__ float softplus_f(float z) {
    // softplus(z) = max(z,0) + log1p(exp(-|z|))  (stable)
    return fmaxf(z, 0.0f) + log1pf(__expf(-fabsf(z)));
}

__global__ __launch_bounds__(256) void rank_loss_partial(
    const float* __restrict__ logits, const int* __restrict__ kd,
    float2* __restrict__ partials, int B)
{
    const int lane = threadIdx.x & 63;
    const int wave = threadIdx.x >> 6;
    const int waveGlobal = blockIdx.x * WAVES_PER_BLOCK + wave;
    const int nWaves = gridDim.x * WAVES_PER_BLOCK;

    float psum = 0.0f;
    float pcnt = 0.0f;

    for (int row = waveGlobal; row < B; row += nWaves) {
        const int base = row * N + lane;
        int k = kd[base];
        int kprev = __shfl_up(k, 1);
        bool newg = (lane == 0) || (k != kprev);
        int start = newg ? lane : -1;
        // inclusive cummax scan across the wave (64 lanes, 6 steps)
        #pragma unroll
        for (int off = 1; off < 64; off <<= 1) {
            int v = __shfl_up(start, off);
            if (lane >= off) start = max(start, v);
        }
        float pred = logits[base];
        // all ordered pairs: lane == index a, loop over b
        #pragma unroll 8
        for (int b = 0; b < N; ++b) {
            int   sb = __shfl(start, b);
            float pb = __shfl(pred, b);
            if (start < sb) {            // y_true[a] > y_true[b]
                psum += softplus_f(pb - pred);  // softplus(-(pred_a - pred_b))
                pcnt += 1.0f;
            }
        }
    }

    // wave reduction (64 lanes)
    #pragma unroll
    for (int off = 32; off; off >>= 1) {
        psum += __shfl_down(psum, off);
        pcnt += __shfl_down(pcnt, off);
    }
    __shared__ float ssum[WAVES_PER_BLOCK], scnt[WAVES_PER_BLOCK];
    if (lane == 0) { ssum[wave] = psum; scnt[wave] = pcnt; }
    __syncthreads();
    if (threadIdx.x == 0) {
        float s = 0.0f, c = 0.0f;
        #pragma unroll
        for (int w = 0; w < WAVES_PER_BLOCK; ++w) { s += ssum[w]; c += scnt[w]; }
        partials[blockIdx.x] = make_float2(s, c);
    }
}

__global__ __launch_bounds__(256) void rank_loss_final(
    const float2* __restrict__ partials, float* __restrict__ out, int nPartials)
{
    const int t = threadIdx.x;
    float s = 0.0f, c = 0.0f;
    for (int i = t; i < nPartials; i += 256) {
        float2 p = partials[i];
        s += p.x; c += p.y;
    }
    #pragma unroll
    for (int off = 32; off; off >>= 1) {
        s += __shfl_down(s, off);
        c += __shfl_down(c, off);
    }
    __shared__ float ss[4], sc[4];
    const int lane = t & 63, wave = t >> 6;
    if (lane == 0) { ss[wave] = s; sc[wave] = c; }
    __syncthreads();
    if (t == 0) {
        float S = 0.0f, C = 0.0f;
        #pragma unroll
        for (int w = 0; w < 4; ++w) { S += ss[w]; C += sc[w]; }
        out[0] = S / C;
    }
}

extern "C" void kernel_launch(void* const* d_in, const int* in_sizes, int n_in,
                              void* d_out, int out_size, void* d_ws, size_t ws_size,
                              hipStream_t stream) {
    const float* logits = (const float*)d_in[0];
    const int*   kd     = (const int*)d_in[1];
    float*       out    = (float*)d_out;
    const int B = in_sizes[1] / N;           // 4096
    float2* partials = (float2*)d_ws;        // needs NBLOCKS*8 = 2 KiB of ws

    rank_loss_partial<<<NBLOCKS, 256, 0, stream>>>(logits, kd, partials, B);
    rank_loss_final<<<1, 256, 0, stream>>>(partials, out, NBLOCKS);
}

// Round 2
// 18.489 us; speedup vs baseline: 4.4722x; 4.4722x over previous
//
#include <hip/hip_runtime.h>
#include <math.h>

// Reranker tie-aware RankNet loss — R2.
// B=4096 rows, n=64. ONE 64-lane wave per row (4096 waves total):
//   - end-of-group index e via reverse min-scan (6 shfl_down steps)
//   - mask (y_true[a] > y_true[b]) == (b > e(a))   [start is non-decreasing]
//   - per-lane pair count = 63 - e  (analytic, no per-pair counting)
//   - softplus via hardware v_exp_f32/v_log_f32 (__expf/__logf)
//   - b-loop fully unrolled: __shfl(pred, const b) -> v_readlane broadcast
// Two-stage deterministic reduction: per-block partials -> finalize kernel.

#define N 64
#define WPB 4  // waves (rows) per block

__global__ __launch_bounds__(256) void rank_loss_partial(
    const float* __restrict__ logits, const int* __restrict__ kd,
    float2* __restrict__ partials, int B)
{
    const int lane = threadIdx.x & 63;
    const int wave = threadIdx.x >> 6;
    const int row  = blockIdx.x * WPB + wave;

    float a0 = 0.f, a1 = 0.f, a2 = 0.f, a3 = 0.f;
    float cnt = 0.f;

    if (row < B) {
        const int base = row * N + lane;
        const int   k    = kd[base];
        const float pred = logits[base];

        // end-of-group: e = min{ j >= lane : is_last(j) }
        const int knext = __shfl_down(k, 1);
        int e = (lane == 63 || k != knext) ? lane : 64;
        #pragma unroll
        for (int off = 1; off < 64; off <<= 1) {
            int v = __shfl_down(e, off);
            if (lane + off < 64) e = min(e, v);
        }
        cnt = (float)(63 - e);  // pairs where this lane is the "winner" a

        #pragma unroll
        for (int b = 0; b < N; ++b) {
            float pb = __shfl(pred, b);        // const lane -> v_readlane
            float z  = pb - pred;              // -(pred_a - pred_b)
            float sp = fmaxf(z, 0.f) + __logf(1.f + __expf(-fabsf(z)));
            float add = (b > e) ? sp : 0.f;
            switch (b & 3) {                   // compile-time after unroll
                case 0: a0 += add; break;
                case 1: a1 += add; break;
                case 2: a2 += add; break;
                default: a3 += add; break;
            }
        }
    }

    float psum = (a0 + a1) + (a2 + a3);
    // wave reduction (64 lanes)
    #pragma unroll
    for (int off = 32; off; off >>= 1) {
        psum += __shfl_down(psum, off);
        cnt  += __shfl_down(cnt,  off);
    }
    __shared__ float ssum[WPB], scnt[WPB];
    if (lane == 0) { ssum[wave] = psum; scnt[wave] = cnt; }
    __syncthreads();
    if (threadIdx.x == 0) {
        float s = 0.f, c = 0.f;
        #pragma unroll
        for (int w = 0; w < WPB; ++w) { s += ssum[w]; c += scnt[w]; }
        partials[blockIdx.x] = make_float2(s, c);
    }
}

__global__ __launch_bounds__(256) void rank_loss_final(
    const float2* __restrict__ partials, float* __restrict__ out, int nPartials)
{
    const int t = threadIdx.x;
    float s = 0.f, c = 0.f;
    for (int i = t; i < nPartials; i += 256) {
        float2 p = partials[i];
        s += p.x; c += p.y;
    }
    #pragma unroll
    for (int off = 32; off; off >>= 1) {
        s += __shfl_down(s, off);
        c += __shfl_down(c, off);
    }
    __shared__ float ss[4], sc[4];
    const int lane = t & 63, wave = t >> 6;
    if (lane == 0) { ss[wave] = s; sc[wave] = c; }
    __syncthreads();
    if (t == 0) {
        float S = 0.f, C = 0.f;
        #pragma unroll
        for (int w = 0; w < 4; ++w) { S += ss[w]; C += sc[w]; }
        out[0] = S / C;
    }
}

extern "C" void kernel_launch(void* const* d_in, const int* in_sizes, int n_in,
                              void* d_out, int out_size, void* d_ws, size_t ws_size,
                              hipStream_t stream) {
    const float* logits = (const float*)d_in[0];
    const int*   kd     = (const int*)d_in[1];
    float*       out    = (float*)d_out;
    const int B = in_sizes[1] / N;              // 4096
    const int nBlocks = (B + WPB - 1) / WPB;    // 1024
    float2* partials = (float2*)d_ws;           // nBlocks * 8 B = 8 KiB

    rank_loss_partial<<<nBlocks, 256, 0, stream>>>(logits, kd, partials, B);
    rank_loss_final<<<1, 256, 0, stream>>>(partials, out, nBlocks);
}